// Round 3
// baseline (418.510 us; speedup 1.0000x reference)
//
#include <hip/hip_runtime.h>
#include <math.h>

// Problem constants (b=8, c=2048, e=64, h=8)
#define NTOK 16384
#define EDIM 64
#define HHE  512   // h*e

// ---------------------------------------------------------------------------
// Kernel 1: q/k/v = x @ W^T + b   (M=16384, N=512 per matrix, K=64)
// R2 version (2-D register tile, 4 cols x 8 tokens) — under test this round.
// ---------------------------------------------------------------------------
__global__ __launch_bounds__(256) void qkv_kernel(
    const float* __restrict__ x,
    const float* __restrict__ Wk, const float* __restrict__ bk,
    const float* __restrict__ Wq, const float* __restrict__ bq,
    const float* __restrict__ Wv, const float* __restrict__ bv,
    float* __restrict__ qb, float* __restrict__ kb, float* __restrict__ vb)
{
    __shared__ float xs[64 * 64];         // 16 KB: 64-token x tile
    __shared__ float ws[128 * 64];        // 32 KB: 128-col W tile

    const int tid  = threadIdx.x;
    const int tok0 = blockIdx.x * 64;
    const int n0   = blockIdx.y * 128;
    const int z    = blockIdx.z;

    const float* W; const float* bias; float* outp;
    if      (z == 0) { W = Wk; bias = bk; outp = kb; }
    else if (z == 1) { W = Wq; bias = bq; outp = qb; }
    else             { W = Wv; bias = bv; outp = vb; }

    // coalesced float4 staging (layouts match global row-major)
    {
        const float4* xg = (const float4*)(x + (size_t)tok0 * 64);
        const float4* wg = (const float4*)(W + (size_t)n0 * 64);
        float4* xl = (float4*)xs;
        float4* wl = (float4*)ws;
        #pragma unroll
        for (int i = 0; i < 4; ++i) xl[i * 256 + tid] = xg[i * 256 + tid];
        #pragma unroll
        for (int i = 0; i < 8; ++i) wl[i * 256 + tid] = wg[i * 256 + tid];
    }
    __syncthreads();

    const int cg = tid & 31;              // col group: 4 cols, 32 groups = 128 cols
    const int tg = tid >> 5;              // token group: 8 tokens, 8 groups = 64 toks

    float acc[4][8];
    #pragma unroll
    for (int c = 0; c < 4; ++c)
        #pragma unroll
        for (int t = 0; t < 8; ++t) acc[c][t] = 0.0f;

    for (int kc = 0; kc < 16; ++kc) {     // K=64 in float4 chunks
        float4 w4[4], x4[8];
        #pragma unroll
        for (int c = 0; c < 4; ++c)
            w4[c] = *(const float4*)&ws[(cg * 4 + c) * 64 + kc * 4];
        #pragma unroll
        for (int t = 0; t < 8; ++t)
            x4[t] = *(const float4*)&xs[(tg * 8 + t) * 64 + kc * 4];
        #pragma unroll
        for (int c = 0; c < 4; ++c)
            #pragma unroll
            for (int t = 0; t < 8; ++t) {
                acc[c][t] = fmaf(w4[c].x, x4[t].x, acc[c][t]);
                acc[c][t] = fmaf(w4[c].y, x4[t].y, acc[c][t]);
                acc[c][t] = fmaf(w4[c].z, x4[t].z, acc[c][t]);
                acc[c][t] = fmaf(w4[c].w, x4[t].w, acc[c][t]);
            }
    }

    const float4 b4 = *(const float4*)&bias[n0 + cg * 4];
    #pragma unroll
    for (int t = 0; t < 8; ++t) {
        float4 o;
        o.x = acc[0][t] + b4.x;
        o.y = acc[1][t] + b4.y;
        o.z = acc[2][t] + b4.z;
        o.w = acc[3][t] + b4.w;
        *(float4*)&outp[(size_t)(tok0 + tg * 8 + t) * HHE + n0 + cg * 4] = o;
    }
}

// ---------------------------------------------------------------------------
// Kernel 2: per-token scores -> entmax_bisect -> att @ v
// EXACT R1 version (24-iter bisection, proven passing) — control variable.
// ---------------------------------------------------------------------------
__device__ __forceinline__ float pgen(float z, float inv) {
    return z > 0.0f ? exp2f(inv * log2f(fmaxf(z, 1e-30f))) : 0.0f;
}

__global__ __launch_bounds__(256) void attn_kernel(
    float* qb,                    // read q, then write res (alias)
    const float* kb, const float* vb,
    const float* alpha_p)
{
    __shared__ float sK[4][HHE];
    __shared__ float sV[4][HHE];
    const int lane = threadIdx.x & 63;
    const int w    = threadIdx.x >> 6;
    const int tok  = blockIdx.x * 4 + w;

    const float alpha = alpha_p[0];
    const float am1   = alpha - 1.0f;

    float qr[8];
    {
        const float* qp = qb + (size_t)tok * HHE;
        const float* kp = kb + (size_t)tok * HHE;
        const float* vp = vb + (size_t)tok * HHE;
        #pragma unroll
        for (int h = 0; h < 8; ++h) {
            qr[h]                 = qp[h * 64 + lane];   // lane i holds q[h][i]
            sK[w][h * 64 + lane]  = kp[h * 64 + lane];
            sV[w][h * 64 + lane]  = vp[h * 64 + lane];
        }
    }
    __syncthreads();   // make whole-wave LDS writes visible for broadcast reads

    // dot row: row[j] = sum_h q[h][lane] * k[h][j]
    float row[64];
    #pragma unroll
    for (int j = 0; j < 64; ++j) row[j] = 0.0f;
    #pragma unroll
    for (int h = 0; h < 8; ++h) {
        const float qh = qr[h];
        #pragma unroll
        for (int j4 = 0; j4 < 16; ++j4) {
            const float4 k4 = *(const float4*)&sK[w][h * 64 + j4 * 4]; // broadcast
            row[j4*4+0] = fmaf(qh, k4.x, row[j4*4+0]);
            row[j4*4+1] = fmaf(qh, k4.y, row[j4*4+1]);
            row[j4*4+2] = fmaf(qh, k4.z, row[j4*4+2]);
            row[j4*4+3] = fmaf(qh, k4.w, row[j4*4+3]);
        }
    }

    // Xa = dot/sqrt(e) * (alpha-1);  1/8 and am1 fold exactly (pow-of-2)
    const float scale = am1 * 0.125f;
    #pragma unroll
    for (int j = 0; j < 64; ++j) row[j] *= scale;

    float mx = row[0];
    #pragma unroll
    for (int j = 1; j < 64; ++j) mx = fmaxf(mx, row[j]);

    float tau_lo = mx - 1.0f;                         // _gp(1, alpha) = 1
    const float tau_hi = mx - exp2f(-6.0f * am1);     // (1/64)^am1
    float dm = tau_hi - tau_lo;
    float tau_m = tau_lo;

    // Bisection. 24 iters: bracketing gives |tau - root| <= 0.875*2^-24 ~ 5e-8.
    if (am1 == 0.5f) {
        // alpha = 1.5: p(z) = max(z,0)^2; z <= 1 always (tau >= mx-1),
        // so clamp-to-[0,1] == max(z,0) and folds into the sub's clamp modifier.
        float f_lo = -1.0f;
        #pragma unroll
        for (int j = 0; j < 64; ++j) {
            float zc = fminf(fmaxf(row[j] - tau_lo, 0.0f), 1.0f);
            f_lo = fmaf(zc, zc, f_lo);
        }
        for (int it = 0; it < 24; ++it) {
            dm *= 0.5f;
            tau_m = tau_lo + dm;
            float f = -1.0f;
            #pragma unroll
            for (int j = 0; j < 64; ++j) {
                float zc = fminf(fmaxf(row[j] - tau_m, 0.0f), 1.0f);
                f = fmaf(zc, zc, f);
            }
            tau_lo = (f * f_lo >= 0.0f) ? tau_m : tau_lo;
        }
        float s = 0.0f;
        #pragma unroll
        for (int j = 0; j < 64; ++j) {
            float zc = fminf(fmaxf(row[j] - tau_m, 0.0f), 1.0f);
            zc = zc * zc;
            row[j] = zc;
            s += zc;
        }
        const float rn = 1.0f / s;
        #pragma unroll
        for (int j = 0; j < 64; ++j) row[j] *= rn;
    } else {
        // faithful general-alpha path (unused for this problem's alpha=1.5)
        const float inv = 1.0f / am1;
        float f_lo = -1.0f;
        #pragma unroll
        for (int j = 0; j < 64; ++j) f_lo += pgen(row[j] - tau_lo, inv);
        for (int it = 0; it < 24; ++it) {
            dm *= 0.5f;
            tau_m = tau_lo + dm;
            float f = -1.0f;
            #pragma unroll
            for (int j = 0; j < 64; ++j) f += pgen(row[j] - tau_m, inv);
            tau_lo = (f * f_lo >= 0.0f) ? tau_m : tau_lo;
        }
        float s = 0.0f;
        #pragma unroll
        for (int j = 0; j < 64; ++j) {
            float pm = pgen(row[j] - tau_m, inv);
            row[j] = pm;
            s += pm;
        }
        const float rn = 1.0f / s;
        #pragma unroll
        for (int j = 0; j < 64; ++j) row[j] *= rn;
    }

    // res[h][lane] = sum_j att[lane][j] * v[h][j]
    float acc[8];
    #pragma unroll
    for (int h = 0; h < 8; ++h) acc[h] = 0.0f;
    #pragma unroll
    for (int h = 0; h < 8; ++h) {
        #pragma unroll
        for (int j4 = 0; j4 < 16; ++j4) {
            const float4 v4 = *(const float4*)&sV[w][h * 64 + j4 * 4]; // broadcast
            acc[h] = fmaf(row[j4*4+0], v4.x, acc[h]);
            acc[h] = fmaf(row[j4*4+1], v4.y, acc[h]);
            acc[h] = fmaf(row[j4*4+2], v4.z, acc[h]);
            acc[h] = fmaf(row[j4*4+3], v4.w, acc[h]);
        }
    }
    float* rp = qb + (size_t)tok * HHE;   // res overwrites q (safe: own wave only)
    #pragma unroll
    for (int h = 0; h < 8; ++h) rp[h * 64 + lane] = acc[h];
}

// ---------------------------------------------------------------------------
// Kernel 3: out = res @ Wu^T + bu   (M=16384, N=64, K=512)
// R2 version (32-token LDS tile, 4 cols x 2 tokens) — under test this round.
// ---------------------------------------------------------------------------
__global__ __launch_bounds__(256) void out_kernel(
    const float* __restrict__ resb, const float* __restrict__ Wu,
    const float* __restrict__ bu, float* __restrict__ out)
{
    __shared__ float rs[32 * HHE];       // 64 KB
    const int tid  = threadIdx.x;
    const int tok0 = blockIdx.x * 32;

    #pragma unroll
    for (int i = 0; i < 16; ++i) {
        int f = i * 256 + tid;           // float4 index, coalesced
        ((float4*)rs)[f] = ((const float4*)(resb + (size_t)tok0 * HHE))[f];
    }
    __syncthreads();

    const int cg = tid & 15;             // col group: 4 cols, 16 groups = 64 cols
    const int tg = tid >> 4;             // token group: 2 tokens, 16 groups = 32

    float acc[4][2];
    #pragma unroll
    for (int c = 0; c < 4; ++c) { acc[c][0] = 0.0f; acc[c][1] = 0.0f; }

    for (int o4 = 0; o4 < 128; ++o4) {   // K=512 in float4 chunks
        float4 w4[4], r4[2];
        #pragma unroll
        for (int c = 0; c < 4; ++c)
            w4[c] = *(const float4*)&Wu[(size_t)(cg * 4 + c) * HHE + o4 * 4];
        #pragma unroll
        for (int t = 0; t < 2; ++t)
            r4[t] = *(const float4*)&rs[(tg * 2 + t) * HHE + o4 * 4];
        #pragma unroll
        for (int c = 0; c < 4; ++c)
            #pragma unroll
            for (int t = 0; t < 2; ++t) {
                acc[c][t] = fmaf(w4[c].x, r4[t].x, acc[c][t]);
                acc[c][t] = fmaf(w4[c].y, r4[t].y, acc[c][t]);
                acc[c][t] = fmaf(w4[c].z, r4[t].z, acc[c][t]);
                acc[c][t] = fmaf(w4[c].w, r4[t].w, acc[c][t]);
            }
    }

    const float4 b4 = *(const float4*)&bu[cg * 4];
    #pragma unroll
    for (int t = 0; t < 2; ++t) {
        float4 o;
        o.x = acc[0][t] + b4.x;
        o.y = acc[1][t] + b4.y;
        o.z = acc[2][t] + b4.z;
        o.w = acc[3][t] + b4.w;
        *(float4*)&out[(size_t)(tok0 + tg * 2 + t) * 64 + cg * 4] = o;
    }
}

// ---------------------------------------------------------------------------
extern "C" void kernel_launch(void* const* d_in, const int* in_sizes, int n_in,
                              void* d_out, int out_size, void* d_ws, size_t ws_size,
                              hipStream_t stream)
{
    const float* x     = (const float*)d_in[0];
    const float* alpha = (const float*)d_in[1];
    const float* Wk    = (const float*)d_in[2];
    const float* bk    = (const float*)d_in[3];
    const float* Wq    = (const float*)d_in[4];
    const float* bq    = (const float*)d_in[5];
    const float* Wv    = (const float*)d_in[6];
    const float* bv    = (const float*)d_in[7];
    const float* Wu    = (const float*)d_in[8];
    const float* bu    = (const float*)d_in[9];
    float* out = (float*)d_out;

    float* ws = (float*)d_ws;
    float* qb = ws;                                  // res aliases q
    float* kb = ws + (size_t)NTOK * HHE;
    float* vb = ws + 2 * (size_t)NTOK * HHE;         // total 96 MB

    qkv_kernel<<<dim3(NTOK / 64, 4, 3), 256, 0, stream>>>(
        x, Wk, bk, Wq, bq, Wv, bv, qb, kb, vb);
    attn_kernel<<<NTOK / 4, 256, 0, stream>>>(qb, kb, vb, alpha);
    out_kernel<<<NTOK / 32, 256, 0, stream>>>(qb, Wu, bu, out);
}